// Round 8
// baseline (198.809 us; speedup 1.0000x reference)
//
#include <hip/hip_runtime.h>
#include <hip/hip_bf16.h>

#define N_ 4
#define L_ 1024
#define E_ 1024
#define H_ 32
#define HD_ 32

typedef unsigned short ushort;
typedef __attribute__((ext_vector_type(8))) short short8;   // bf16 x8 MFMA A/B frag
typedef __attribute__((ext_vector_type(4))) float float4v;  // MFMA C/D frag
typedef __attribute__((ext_vector_type(2))) unsigned int uint2v;

// branch-free RNE f32->bf16 (valid for all finite, any sign; no NaN inputs here)
__device__ __forceinline__ unsigned packbf2(float a, float b) {
    unsigned ua = __float_as_uint(a);
    unsigned ub = __float_as_uint(b);
    ua += 0x7FFFu + ((ua >> 16) & 1u);
    ub += 0x7FFFu + ((ub >> 16) & 1u);
    return (ua >> 16) | (ub & 0xFFFF0000u);
}

__device__ __forceinline__ ushort f2b(float f) {
    unsigned u = __float_as_uint(f);
    u += 0x7FFFu + ((u >> 16) & 1u);
    return (ushort)(u >> 16);
}

__device__ __forceinline__ float fast_exp2(float x) {
#if __has_builtin(__builtin_amdgcn_exp2f)
    return __builtin_amdgcn_exp2f(x);        // raw v_exp_f32 (2^x)
#else
    return __expf(x * 0.69314718056f);
#endif
}

// load 8 consecutive fp32, convert to bf16x8 frag (RNE)
__device__ __forceinline__ short8 cvt8(const float* __restrict__ p) {
    float4v a = *(const float4v*)p;
    float4v b = *(const float4v*)(p + 4);
    union { unsigned u[4]; short8 s; } r;
    r.u[0] = packbf2(a[0], a[1]); r.u[1] = packbf2(a[2], a[3]);
    r.u[2] = packbf2(b[0], b[1]); r.u[3] = packbf2(b[2], b[3]);
    return r.s;
}

// ---------------------------------------------------------------------------
// Kernel 1: per-head projections via MFMA, no LDS. Converts W inline (L2-hot),
// fills bias_f (h==0 blocks). V computed with swapped operands so the V^T
// store is tok-major across lanes (coalesced 32B runs vs 2B scatter).
// grid (L/64, H, N), block 256.
// ---------------------------------------------------------------------------
__global__ __launch_bounds__(256) void proj_kernel(
    const float* __restrict__ v_in, const float* __restrict__ k_in,
    const float* __restrict__ q_in,
    const float* __restrict__ Wv, const float* __restrict__ Wk,
    const float* __restrict__ Wq, const int* __restrict__ mask,
    ushort* __restrict__ vt_ws, ushort* __restrict__ k_ws,
    ushort* __restrict__ q_ws, float* __restrict__ bias_f)
{
    const int n = blockIdx.z, h = blockIdx.y, l0 = blockIdx.x * 64;
    const int t = threadIdx.x, wave = t >> 6, lane = t & 63;
    const int m = lane & 15, g = lane >> 4;

    // mask -> additive bias, done once (h==0 slice of the grid)
    if (h == 0 && t < 64)
        bias_f[n * L_ + l0 + t] = (mask[n * L_ + l0 + t] == 0) ? -1e30f : 0.0f;

    const size_t row = (size_t)(n * L_) + l0 + wave * 16 + m;
    const float* src[3] = {v_in, k_in, q_in};
    const float* wsrc[3] = {Wv, Wk, Wq};

    short8 Xf[3], Wf[3][2];
#pragma unroll
    for (int mat = 0; mat < 3; ++mat) {
        Xf[mat] = cvt8(src[mat] + row * E_ + h * HD_ + g * 8);
#pragma unroll
        for (int dt = 0; dt < 2; ++dt)
            Wf[mat][dt] = cvt8(wsrc[mat] + (dt * 16 + m) * HD_ + g * 8);
    }

    const size_t obase = (size_t)(n * H_ + h) * L_;
    const size_t vb = (size_t)(n * H_ + h) * HD_ * L_;

    // q,k: D[tok][d] = X·W^T  (A=X, B=W)
#pragma unroll
    for (int mat = 1; mat < 3; ++mat) {
        ushort* outp = (mat == 1) ? k_ws : q_ws;
#pragma unroll
        for (int dt = 0; dt < 2; ++dt) {
            float4v z = float4v{0.f, 0.f, 0.f, 0.f};
            float4v acc = __builtin_amdgcn_mfma_f32_16x16x32_bf16(Xf[mat], Wf[mat][dt], z, 0, 0, 0);
#pragma unroll
            for (int r = 0; r < 4; ++r) {
                int tok = l0 + wave * 16 + g * 4 + r;
                outp[(obase + tok) * HD_ + dt * 16 + m] = f2b(acc[r]);
            }
        }
    }
    // v: D[d][tok] = W·X^T (A=W, B=X) -> lane m = tok (coalesced vt store)
#pragma unroll
    for (int dt = 0; dt < 2; ++dt) {
        float4v z = float4v{0.f, 0.f, 0.f, 0.f};
        float4v acc = __builtin_amdgcn_mfma_f32_16x16x32_bf16(Wf[0][dt], Xf[0], z, 0, 0, 0);
#pragma unroll
        for (int r = 0; r < 4; ++r) {
            int d = dt * 16 + g * 4 + r;
            vt_ws[vb + (size_t)d * L_ + l0 + wave * 16 + m] = f2b(acc[r]);
        }
    }
}

// ---------------------------------------------------------------------------
// Kernel 2: attention, barrier-free, XCD-swizzled, S^T orientation, 2 Q-tiles
// per wave, SOFTWARE-PIPELINED: PV lags one chunk behind QK/exp via a
// double-buffered wave-private P tile, so the exp->pack->LDS write->read->PV
// chain never stalls (read hits data written a full iteration earlier) and
// V-loads issue ~2000 cyc before use.
// grid 1024 blocks (8 q-tiles x 128 heads), block 256.
// ---------------------------------------------------------------------------
__global__ __launch_bounds__(256, 4) void attn_kernel(
    const ushort* __restrict__ q_ws, const ushort* __restrict__ k_ws,
    const ushort* __restrict__ vt_ws, const float* __restrict__ bias_f,
    ushort* __restrict__ x_ws)
{
    const int B = blockIdx.x;
    const int head = ((B >> 6) << 3) + (B & 7);   // 8 blocks/head share an XCD
    const int qt = (B >> 3) & 7;
    const int n = head >> 5, h = head & 31, q0 = qt * 128;

    const int t = threadIdx.x, wave = t >> 6, lane = t & 63;
    const int m = lane & 15, g = lane >> 4;

    __shared__ ushort sP[4][2][2][16][72];   // [wave][buf][tile][q][tok]

    const size_t base = (size_t)(n * H_ + h) * L_;
    const ushort* vb_p = vt_ws + (size_t)(n * H_ + h) * HD_ * L_;

    short8 qfa = *(const short8*)(q_ws + (base + q0 + wave * 16 + m) * HD_ + g * 8);
    short8 qfb = *(const short8*)(q_ws + (base + q0 + 64 + wave * 16 + m) * HD_ + g * 8);

    float4v Oa[2], Ob[2];
    Oa[0] = float4v{0.f,0.f,0.f,0.f}; Oa[1] = float4v{0.f,0.f,0.f,0.f};
    Ob[0] = float4v{0.f,0.f,0.f,0.f}; Ob[1] = float4v{0.f,0.f,0.f,0.f};
    float rsa[4] = {0.f,0.f,0.f,0.f}, rsb[4] = {0.f,0.f,0.f,0.f};
    const float k1 = 0.03125f * 1.44269504f;   // (1/sqrt(E)) * log2(e)

    ushort* const pa0 = &sP[wave][0][0][m][0];
    ushort* const pa1 = &sP[wave][1][0][m][0];
    ushort* const pb0 = &sP[wave][0][1][m][0];
    ushort* const pb1 = &sP[wave][1][1][m][0];

    const ushort* kp = k_ws + base * HD_ + (size_t)m * HD_ + g * 8;   // +tok*HD
    const ushort* vp = vb_p + (size_t)m * L_ + g * 8;                 // +db*16*L+tok
    const float*  bp = bias_f + n * L_ + g * 4;

    // --- prologue: K(0) frags, stage1(chunk 0) into buf0 ---
    short8 kf[4];
#pragma unroll
    for (int nb = 0; nb < 4; ++nb)
        kf[nb] = *(const short8*)(kp + (size_t)nb * 16 * HD_);
    kp += (size_t)64 * HD_;

    float4v Sa[4], Sb[4];
#pragma unroll
    for (int nb = 0; nb < 4; ++nb) {
        float4v z = float4v{0.f,0.f,0.f,0.f};
        Sa[nb] = __builtin_amdgcn_mfma_f32_16x16x32_bf16(kf[nb], qfa, z, 0, 0, 0);
        Sb[nb] = __builtin_amdgcn_mfma_f32_16x16x32_bf16(kf[nb], qfb, z, 0, 0, 0);
    }
#pragma unroll
    for (int nb = 0; nb < 4; ++nb)
        kf[nb] = *(const short8*)(kp + (size_t)nb * 16 * HD_);   // prefetch K(1)
    kp += (size_t)64 * HD_;
#pragma unroll
    for (int nb = 0; nb < 4; ++nb) {
        float4v b4 = *(const float4v*)(bp + nb * 16);
        float a0 = fast_exp2(fmaf(Sa[nb][0], k1, b4[0]));
        float a1 = fast_exp2(fmaf(Sa[nb][1], k1, b4[1]));
        float a2 = fast_exp2(fmaf(Sa[nb][2], k1, b4[2]));
        float a3 = fast_exp2(fmaf(Sa[nb][3], k1, b4[3]));
        rsa[0] += a0; rsa[1] += a1; rsa[2] += a2; rsa[3] += a3;
        uint2v pk; pk[0] = packbf2(a0, a1); pk[1] = packbf2(a2, a3);
        *(uint2v*)(pa0 + nb * 16 + g * 4) = pk;
        float e0 = fast_exp2(fmaf(Sb[nb][0], k1, b4[0]));
        float e1 = fast_exp2(fmaf(Sb[nb][1], k1, b4[1]));
        float e2 = fast_exp2(fmaf(Sb[nb][2], k1, b4[2]));
        float e3 = fast_exp2(fmaf(Sb[nb][3], k1, b4[3]));
        rsb[0] += e0; rsb[1] += e1; rsb[2] += e2; rsb[3] += e3;
        uint2v qk; qk[0] = packbf2(e0, e1); qk[1] = packbf2(e2, e3);
        *(uint2v*)(pb0 + nb * 16 + g * 4) = qk;
    }
    bp += 64;

    // --- pipelined main loop: stage1(c) + PV(c-1) ---
    for (int c = 1; c < 16; ++c) {
        // V frags for chunk c-1 (PV below)
        short8 vf[2][2];
#pragma unroll
        for (int kb = 0; kb < 2; ++kb)
#pragma unroll
            for (int db = 0; db < 2; ++db)
                vf[kb][db] = *(const short8*)(vp + (size_t)db * 16 * L_ + kb * 32);
        vp += 64;

        // QK(c)
#pragma unroll
        for (int nb = 0; nb < 4; ++nb) {
            float4v z = float4v{0.f,0.f,0.f,0.f};
            Sa[nb] = __builtin_amdgcn_mfma_f32_16x16x32_bf16(kf[nb], qfa, z, 0, 0, 0);
            Sb[nb] = __builtin_amdgcn_mfma_f32_16x16x32_bf16(kf[nb], qfb, z, 0, 0, 0);
        }

        // PV(c-1): reads buf written LAST iteration -> no lgkm stall
        const ushort* ra = (c & 1) ? pa0 : pa1;
        const ushort* rb = (c & 1) ? pb0 : pb1;
#pragma unroll
        for (int kb = 0; kb < 2; ++kb) {
            short8 af = *(const short8*)(ra + kb * 32 + g * 8);
            Oa[0] = __builtin_amdgcn_mfma_f32_16x16x32_bf16(af, vf[kb][0], Oa[0], 0, 0, 0);
            Oa[1] = __builtin_amdgcn_mfma_f32_16x16x32_bf16(af, vf[kb][1], Oa[1], 0, 0, 0);
        }
#pragma unroll
        for (int kb = 0; kb < 2; ++kb) {
            short8 bf = *(const short8*)(rb + kb * 32 + g * 8);
            Ob[0] = __builtin_amdgcn_mfma_f32_16x16x32_bf16(bf, vf[kb][0], Ob[0], 0, 0, 0);
            Ob[1] = __builtin_amdgcn_mfma_f32_16x16x32_bf16(bf, vf[kb][1], Ob[1], 0, 0, 0);
        }

        // prefetch K(c+1) (kf regs dead after QK above; last iter overruns
        // into vt_ws region - allocated, values unused)
#pragma unroll
        for (int nb = 0; nb < 4; ++nb)
            kf[nb] = *(const short8*)(kp + (size_t)nb * 16 * HD_);
        kp += (size_t)64 * HD_;

        // exp/pack/write chunk c -> buf[c&1]
        ushort* wa = (c & 1) ? pa1 : pa0;
        ushort* wb = (c & 1) ? pb1 : pb0;
#pragma unroll
        for (int nb = 0; nb < 4; ++nb) {
            float4v b4 = *(const float4v*)(bp + nb * 16);
            float a0 = fast_exp2(fmaf(Sa[nb][0], k1, b4[0]));
            float a1 = fast_exp2(fmaf(Sa[nb][1], k1, b4[1]));
            float a2 = fast_exp2(fmaf(Sa[nb][2], k1, b4[2]));
            float a3 = fast_exp2(fmaf(Sa[nb][3], k1, b4[3]));
            rsa[0] += a0; rsa[1] += a1; rsa[2] += a2; rsa[3] += a3;
            uint2v pk; pk[0] = packbf2(a0, a1); pk[1] = packbf2(a2, a3);
            *(uint2v*)(wa + nb * 16 + g * 4) = pk;
            float e0 = fast_exp2(fmaf(Sb[nb][0], k1, b4[0]));
            float e1 = fast_exp2(fmaf(Sb[nb][1], k1, b4[1]));
            float e2 = fast_exp2(fmaf(Sb[nb][2], k1, b4[2]));
            float e3 = fast_exp2(fmaf(Sb[nb][3], k1, b4[3]));
            rsb[0] += e0; rsb[1] += e1; rsb[2] += e2; rsb[3] += e3;
            uint2v qk; qk[0] = packbf2(e0, e1); qk[1] = packbf2(e2, e3);
            *(uint2v*)(wb + nb * 16 + g * 4) = qk;
        }
        bp += 64;
    }

    // --- epilogue: PV(15) from buf1 ---
    {
        short8 vf[2][2];
#pragma unroll
        for (int kb = 0; kb < 2; ++kb)
#pragma unroll
            for (int db = 0; db < 2; ++db)
                vf[kb][db] = *(const short8*)(vp + (size_t)db * 16 * L_ + kb * 32);
#pragma unroll
        for (int kb = 0; kb < 2; ++kb) {
            short8 af = *(const short8*)(pa1 + kb * 32 + g * 8);
            Oa[0] = __builtin_amdgcn_mfma_f32_16x16x32_bf16(af, vf[kb][0], Oa[0], 0, 0, 0);
            Oa[1] = __builtin_amdgcn_mfma_f32_16x16x32_bf16(af, vf[kb][1], Oa[1], 0, 0, 0);
        }
#pragma unroll
        for (int kb = 0; kb < 2; ++kb) {
            short8 bf = *(const short8*)(pb1 + kb * 32 + g * 8);
            Ob[0] = __builtin_amdgcn_mfma_f32_16x16x32_bf16(bf, vf[kb][0], Ob[0], 0, 0, 0);
            Ob[1] = __builtin_amdgcn_mfma_f32_16x16x32_bf16(bf, vf[kb][1], Ob[1], 0, 0, 0);
        }
    }

    // row-sums, redistribute, normalize, store
    float ra = (rsa[0] + rsa[1]) + (rsa[2] + rsa[3]);
    float rb = (rsb[0] + rsb[1]) + (rsb[2] + rsb[3]);
    ra += __shfl_xor(ra, 16, 64); ra += __shfl_xor(ra, 32, 64);
    rb += __shfl_xor(rb, 16, 64); rb += __shfl_xor(rb, 32, 64);
#pragma unroll
    for (int r = 0; r < 4; ++r) {
        float inva = 1.f / __shfl(ra, g * 4 + r, 64);
        float invb = 1.f / __shfl(rb, g * 4 + r, 64);
        size_t rowa = (size_t)n * L_ + q0 + wave * 16 + g * 4 + r;
        size_t rowb = rowa + 64;
#pragma unroll
        for (int db = 0; db < 2; ++db) {
            x_ws[rowa * E_ + h * HD_ + db * 16 + m] = f2b(Oa[db][r] * inva);
            x_ws[rowb * E_ + h * HD_ + db * 16 + m] = f2b(Ob[db][r] * invb);
        }
    }
}

// ---------------------------------------------------------------------------
// Kernel 3: C = X(bf16 4096x1024) @ Wo^T(fp32->bf16 inline) + bo, fp32 out.
// 64x64 tile, BK=64, 1024 blocks, XCD-swizzled; register-prefetch pipeline
// (next k-tile loaded during compute).
// ---------------------------------------------------------------------------
__global__ __launch_bounds__(256) void out_gemm_kernel(
    const ushort* __restrict__ X, const float* __restrict__ Wo,
    const float* __restrict__ bo, float* __restrict__ C)
{
    const int B = blockIdx.x;
    const int it = ((B >> 7) << 3) + (B & 7);   // 0..63
    const int jt = (B >> 3) & 15;               // 0..15
    const int i0 = it * 64, j0 = jt * 64;

    const int t = threadIdx.x, wave = t >> 6, lane = t & 63;
    const int m = lane & 15, g = lane >> 4;

    __shared__ ushort sA[64][72];
    __shared__ ushort sB[64][72];

    float4v acc[4];
#pragma unroll
    for (int nb = 0; nb < 4; ++nb) acc[nb] = float4v{0.f,0.f,0.f,0.f};

    const int r0 = t >> 2;          // 0..63
    const int c0 = (t & 3) * 16;    // 0..48

    const ushort* xp = X + (size_t)(i0 + r0) * E_ + c0;
    const float*  wp = Wo + (size_t)(j0 + r0) * E_ + c0;

    short8 xr0 = *(const short8*)xp;
    short8 xr1 = *(const short8*)(xp + 8);
    float4v wr0 = *(const float4v*)wp;
    float4v wr1 = *(const float4v*)(wp + 4);
    float4v wr2 = *(const float4v*)(wp + 8);
    float4v wr3 = *(const float4v*)(wp + 12);

    for (int k0 = 0; k0 < E_; k0 += 64) {
        __syncthreads();
        *(short8*)&sA[r0][c0]     = xr0;
        *(short8*)&sA[r0][c0 + 8] = xr1;
        union { unsigned u[4]; short8 s; } b0, b1;
        b0.u[0] = packbf2(wr0[0], wr0[1]); b0.u[1] = packbf2(wr0[2], wr0[3]);
        b0.u[2] = packbf2(wr1[0], wr1[1]); b0.u[3] = packbf2(wr1[2], wr1[3]);
        b1.u[0] = packbf2(wr2[0], wr2[1]); b1.u[1] = packbf2(wr2[2], wr2[3]);
        b1.u[2] = packbf2(wr3[0], wr3[1]); b1.u[3] = packbf2(wr3[2], wr3[3]);
        *(short8*)&sB[r0][c0]     = b0.s;
        *(short8*)&sB[r0][c0 + 8] = b1.s;
        __syncthreads();
        if (k0 + 64 < E_) {   // uniform; prefetch next k-tile during compute
            xr0 = *(const short8*)(xp + k0 + 64);
            xr1 = *(const short8*)(xp + k0 + 72);
            wr0 = *(const float4v*)(wp + k0 + 64);
            wr1 = *(const float4v*)(wp + k0 + 68);
            wr2 = *(const float4v*)(wp + k0 + 72);
            wr3 = *(const float4v*)(wp + k0 + 76);
        }
#pragma unroll
        for (int kb = 0; kb < 2; ++kb) {
            short8 afr = *(const short8*)&sA[wave * 16 + m][kb * 32 + g * 8];
#pragma unroll
            for (int nb = 0; nb < 4; ++nb) {
                short8 bfr = *(const short8*)&sB[nb * 16 + m][kb * 32 + g * 8];
                acc[nb] = __builtin_amdgcn_mfma_f32_16x16x32_bf16(afr, bfr, acc[nb], 0, 0, 0);
            }
        }
    }

#pragma unroll
    for (int nb = 0; nb < 4; ++nb) {
        int col = j0 + nb * 16 + m;
        float bias = bo[col];
#pragma unroll
        for (int r = 0; r < 4; ++r) {
            int rowi = i0 + wave * 16 + g * 4 + r;
            C[(size_t)rowi * E_ + col] = acc[nb][r] + bias;
        }
    }
}

// ---------------------------------------------------------------------------
extern "C" void kernel_launch(void* const* d_in, const int* in_sizes, int n_in,
                              void* d_out, int out_size, void* d_ws, size_t ws_size,
                              hipStream_t stream) {
    const float* values = (const float*)d_in[0];
    const float* keys   = (const float*)d_in[1];
    const float* query  = (const float*)d_in[2];
    const int*   mask   = (const int*)d_in[3];
    const float* Wv     = (const float*)d_in[4];
    const float* Wk     = (const float*)d_in[5];
    const float* Wq     = (const float*)d_in[6];
    const float* Wo     = (const float*)d_in[7];
    const float* bo     = (const float*)d_in[8];
    float* out = (float*)d_out;

    const size_t M4 = (size_t)N_ * H_ * L_ * HD_;   // 4 Mi elements
    ushort* q_ws   = (ushort*)d_ws;
    ushort* k_ws   = q_ws + M4;
    ushort* vt_ws  = k_ws + M4;
    ushort* x_ws   = vt_ws + M4;
    float*  bias_f = (float*)(x_ws + M4);           // 4096 floats, 16B-aligned

    proj_kernel<<<dim3(L_ / 64, H_, N_), 256, 0, stream>>>(
        values, keys, query, Wv, Wk, Wq, mask, vt_ws, k_ws, q_ws, bias_f);

    attn_kernel<<<dim3(1024), 256, 0, stream>>>(
        q_ws, k_ws, vt_ws, bias_f, x_ws);

    out_gemm_kernel<<<dim3(1024), 256, 0, stream>>>(
        x_ws, Wo, bo, out);
}

// Round 9
// 192.641 us; speedup vs baseline: 1.0320x; 1.0320x over previous
//
#include <hip/hip_runtime.h>
#include <hip/hip_bf16.h>

#define N_ 4
#define L_ 1024
#define E_ 1024
#define H_ 32
#define HD_ 32

typedef unsigned short ushort;
typedef __attribute__((ext_vector_type(8))) short short8;   // bf16 x8 MFMA A/B frag
typedef __attribute__((ext_vector_type(4))) float float4v;  // MFMA C/D frag
typedef __attribute__((ext_vector_type(2))) unsigned int uint2v;
typedef __attribute__((ext_vector_type(2))) float float2v;

// branch-free RNE f32->bf16 (finite inputs)
__device__ __forceinline__ unsigned packbf2(float a, float b) {
    unsigned ua = __float_as_uint(a);
    unsigned ub = __float_as_uint(b);
    ua += 0x7FFFu + ((ua >> 16) & 1u);
    ub += 0x7FFFu + ((ub >> 16) & 1u);
    return (ua >> 16) | (ub & 0xFFFF0000u);
}

__device__ __forceinline__ ushort f2b(float f) {
    unsigned u = __float_as_uint(f);
    u += 0x7FFFu + ((u >> 16) & 1u);
    return (ushort)(u >> 16);
}

__device__ __forceinline__ float fast_exp2(float x) {
#if __has_builtin(__builtin_amdgcn_exp2f)
    return __builtin_amdgcn_exp2f(x);        // raw v_exp_f32 (2^x)
#else
    return __expf(x * 0.69314718056f);
#endif
}

// load 8 consecutive fp32, convert to bf16x8 frag (RNE)
__device__ __forceinline__ short8 cvt8(const float* __restrict__ p) {
    float4v a = *(const float4v*)p;
    float4v b = *(const float4v*)(p + 4);
    union { unsigned u[4]; short8 s; } r;
    r.u[0] = packbf2(a[0], a[1]); r.u[1] = packbf2(a[2], a[3]);
    r.u[2] = packbf2(b[0], b[1]); r.u[3] = packbf2(b[2], b[3]);
    return r.s;
}

// ---------------------------------------------------------------------------
// Kernel 1: per-head projections via MFMA, no LDS.  ALL three matmuls use
// swapped operands (A=W, B=X) -> D[d][tok]: in-lane r = consecutive d for
// q/k (one 8B packed store per dt -> fully coalesced 64B runs), and lane
// m = tok for v (32B runs).  Also converts Wo -> bf16 (1 dword/thread) and
// fills bias_f (h==0 slice).
// grid (L/64, H, N), block 256.
// ---------------------------------------------------------------------------
__global__ __launch_bounds__(256) void proj_kernel(
    const float* __restrict__ v_in, const float* __restrict__ k_in,
    const float* __restrict__ q_in,
    const float* __restrict__ Wv, const float* __restrict__ Wk,
    const float* __restrict__ Wq, const float* __restrict__ Wo,
    const int* __restrict__ mask,
    ushort* __restrict__ vt_ws, ushort* __restrict__ k_ws,
    ushort* __restrict__ q_ws, ushort* __restrict__ wo_bf,
    float* __restrict__ bias_f)
{
    const int n = blockIdx.z, h = blockIdx.y, l0 = blockIdx.x * 64;
    const int t = threadIdx.x, wave = t >> 6, lane = t & 63;
    const int m = lane & 15, g = lane >> 4;

    // Wo -> bf16: linear block id covers 1Mi elements, 2 per thread
    {
        const int lb = ((n * H_ + h) << 4) + blockIdx.x;   // 0..2047
        const int i = lb * 256 + t;                        // dword index
        float2v w2 = *(const float2v*)(Wo + 2 * i);
        ((unsigned*)wo_bf)[i] = packbf2(w2[0], w2[1]);
    }
    // mask -> additive bias, done once (h==0 slice)
    if (h == 0 && t < 64)
        bias_f[n * L_ + l0 + t] = (mask[n * L_ + l0 + t] == 0) ? -1e30f : 0.0f;

    const size_t row = (size_t)(n * L_) + l0 + wave * 16 + m;
    const float* src[3] = {v_in, k_in, q_in};
    const float* wsrc[3] = {Wv, Wk, Wq};

    short8 Xf[3], Wf[3][2];
#pragma unroll
    for (int mat = 0; mat < 3; ++mat) {
        Xf[mat] = cvt8(src[mat] + row * E_ + h * HD_ + g * 8);
#pragma unroll
        for (int dt = 0; dt < 2; ++dt)
            Wf[mat][dt] = cvt8(wsrc[mat] + (dt * 16 + m) * HD_ + g * 8);
    }

    const size_t obase = (size_t)(n * H_ + h) * L_;
    const size_t vb = (size_t)(n * H_ + h) * HD_ * L_;
    const int tok = l0 + wave * 16 + m;   // this lane's token (D col = m)

    // q,k: D[d][tok]; lane's 4 accs are consecutive d -> one 8B store per dt
#pragma unroll
    for (int mat = 1; mat < 3; ++mat) {
        ushort* outp = (mat == 1) ? k_ws : q_ws;
#pragma unroll
        for (int dt = 0; dt < 2; ++dt) {
            float4v z = float4v{0.f, 0.f, 0.f, 0.f};
            float4v acc = __builtin_amdgcn_mfma_f32_16x16x32_bf16(Wf[mat][dt], Xf[mat], z, 0, 0, 0);
            uint2v pk;
            pk[0] = packbf2(acc[0], acc[1]);
            pk[1] = packbf2(acc[2], acc[3]);
            *(uint2v*)(outp + (obase + tok) * HD_ + dt * 16 + g * 4) = pk;
        }
    }
    // v: D[d][tok] -> vt[d][tok], lane m = tok (coalesced 32B runs)
#pragma unroll
    for (int dt = 0; dt < 2; ++dt) {
        float4v z = float4v{0.f, 0.f, 0.f, 0.f};
        float4v acc = __builtin_amdgcn_mfma_f32_16x16x32_bf16(Wf[0][dt], Xf[0], z, 0, 0, 0);
#pragma unroll
        for (int r = 0; r < 4; ++r) {
            int d = dt * 16 + g * 4 + r;
            vt_ws[vb + (size_t)d * L_ + tok] = f2b(acc[r]);
        }
    }
}

// ---------------------------------------------------------------------------
// Kernel 2: attention — UNCHANGED from round 8 (controlled experiment).
// Barrier-free, XCD-swizzled, S^T orientation, 2 Q-tiles/wave, PV lags one
// chunk via double-buffered wave-private P tile.
// grid 1024 blocks, block 256.
// ---------------------------------------------------------------------------
__global__ __launch_bounds__(256, 4) void attn_kernel(
    const ushort* __restrict__ q_ws, const ushort* __restrict__ k_ws,
    const ushort* __restrict__ vt_ws, const float* __restrict__ bias_f,
    ushort* __restrict__ x_ws)
{
    const int B = blockIdx.x;
    const int head = ((B >> 6) << 3) + (B & 7);
    const int qt = (B >> 3) & 7;
    const int n = head >> 5, h = head & 31, q0 = qt * 128;

    const int t = threadIdx.x, wave = t >> 6, lane = t & 63;
    const int m = lane & 15, g = lane >> 4;

    __shared__ ushort sP[4][2][2][16][72];   // [wave][buf][tile][q][tok]

    const size_t base = (size_t)(n * H_ + h) * L_;
    const ushort* vb_p = vt_ws + (size_t)(n * H_ + h) * HD_ * L_;

    short8 qfa = *(const short8*)(q_ws + (base + q0 + wave * 16 + m) * HD_ + g * 8);
    short8 qfb = *(const short8*)(q_ws + (base + q0 + 64 + wave * 16 + m) * HD_ + g * 8);

    float4v Oa[2], Ob[2];
    Oa[0] = float4v{0.f,0.f,0.f,0.f}; Oa[1] = float4v{0.f,0.f,0.f,0.f};
    Ob[0] = float4v{0.f,0.f,0.f,0.f}; Ob[1] = float4v{0.f,0.f,0.f,0.f};
    float rsa[4] = {0.f,0.f,0.f,0.f}, rsb[4] = {0.f,0.f,0.f,0.f};
    const float k1 = 0.03125f * 1.44269504f;

    ushort* const pa0 = &sP[wave][0][0][m][0];
    ushort* const pa1 = &sP[wave][1][0][m][0];
    ushort* const pb0 = &sP[wave][0][1][m][0];
    ushort* const pb1 = &sP[wave][1][1][m][0];

    const ushort* kp = k_ws + base * HD_ + (size_t)m * HD_ + g * 8;
    const ushort* vp = vb_p + (size_t)m * L_ + g * 8;
    const float*  bp = bias_f + n * L_ + g * 4;

    short8 kf[4];
#pragma unroll
    for (int nb = 0; nb < 4; ++nb)
        kf[nb] = *(const short8*)(kp + (size_t)nb * 16 * HD_);
    kp += (size_t)64 * HD_;

    float4v Sa[4], Sb[4];
#pragma unroll
    for (int nb = 0; nb < 4; ++nb) {
        float4v z = float4v{0.f,0.f,0.f,0.f};
        Sa[nb] = __builtin_amdgcn_mfma_f32_16x16x32_bf16(kf[nb], qfa, z, 0, 0, 0);
        Sb[nb] = __builtin_amdgcn_mfma_f32_16x16x32_bf16(kf[nb], qfb, z, 0, 0, 0);
    }
#pragma unroll
    for (int nb = 0; nb < 4; ++nb)
        kf[nb] = *(const short8*)(kp + (size_t)nb * 16 * HD_);
    kp += (size_t)64 * HD_;
#pragma unroll
    for (int nb = 0; nb < 4; ++nb) {
        float4v b4 = *(const float4v*)(bp + nb * 16);
        float a0 = fast_exp2(fmaf(Sa[nb][0], k1, b4[0]));
        float a1 = fast_exp2(fmaf(Sa[nb][1], k1, b4[1]));
        float a2 = fast_exp2(fmaf(Sa[nb][2], k1, b4[2]));
        float a3 = fast_exp2(fmaf(Sa[nb][3], k1, b4[3]));
        rsa[0] += a0; rsa[1] += a1; rsa[2] += a2; rsa[3] += a3;
        uint2v pk; pk[0] = packbf2(a0, a1); pk[1] = packbf2(a2, a3);
        *(uint2v*)(pa0 + nb * 16 + g * 4) = pk;
        float e0 = fast_exp2(fmaf(Sb[nb][0], k1, b4[0]));
        float e1 = fast_exp2(fmaf(Sb[nb][1], k1, b4[1]));
        float e2 = fast_exp2(fmaf(Sb[nb][2], k1, b4[2]));
        float e3 = fast_exp2(fmaf(Sb[nb][3], k1, b4[3]));
        rsb[0] += e0; rsb[1] += e1; rsb[2] += e2; rsb[3] += e3;
        uint2v qk; qk[0] = packbf2(e0, e1); qk[1] = packbf2(e2, e3);
        *(uint2v*)(pb0 + nb * 16 + g * 4) = qk;
    }
    bp += 64;

    for (int c = 1; c < 16; ++c) {
        short8 vf[2][2];
#pragma unroll
        for (int kb = 0; kb < 2; ++kb)
#pragma unroll
            for (int db = 0; db < 2; ++db)
                vf[kb][db] = *(const short8*)(vp + (size_t)db * 16 * L_ + kb * 32);
        vp += 64;

#pragma unroll
        for (int nb = 0; nb < 4; ++nb) {
            float4v z = float4v{0.f,0.f,0.f,0.f};
            Sa[nb] = __builtin_amdgcn_mfma_f32_16x16x32_bf16(kf[nb], qfa, z, 0, 0, 0);
            Sb[nb] = __builtin_amdgcn_mfma_f32_16x16x32_bf16(kf[nb], qfb, z, 0, 0, 0);
        }

        const ushort* ra = (c & 1) ? pa0 : pa1;
        const ushort* rb = (c & 1) ? pb0 : pb1;
#pragma unroll
        for (int kb = 0; kb < 2; ++kb) {
            short8 af = *(const short8*)(ra + kb * 32 + g * 8);
            Oa[0] = __builtin_amdgcn_mfma_f32_16x16x32_bf16(af, vf[kb][0], Oa[0], 0, 0, 0);
            Oa[1] = __builtin_amdgcn_mfma_f32_16x16x32_bf16(af, vf[kb][1], Oa[1], 0, 0, 0);
        }
#pragma unroll
        for (int kb = 0; kb < 2; ++kb) {
            short8 bf = *(const short8*)(rb + kb * 32 + g * 8);
            Ob[0] = __builtin_amdgcn_mfma_f32_16x16x32_bf16(bf, vf[kb][0], Ob[0], 0, 0, 0);
            Ob[1] = __builtin_amdgcn_mfma_f32_16x16x32_bf16(bf, vf[kb][1], Ob[1], 0, 0, 0);
        }

#pragma unroll
        for (int nb = 0; nb < 4; ++nb)
            kf[nb] = *(const short8*)(kp + (size_t)nb * 16 * HD_);
        kp += (size_t)64 * HD_;

        ushort* wa = (c & 1) ? pa1 : pa0;
        ushort* wb = (c & 1) ? pb1 : pb0;
#pragma unroll
        for (int nb = 0; nb < 4; ++nb) {
            float4v b4 = *(const float4v*)(bp + nb * 16);
            float a0 = fast_exp2(fmaf(Sa[nb][0], k1, b4[0]));
            float a1 = fast_exp2(fmaf(Sa[nb][1], k1, b4[1]));
            float a2 = fast_exp2(fmaf(Sa[nb][2], k1, b4[2]));
            float a3 = fast_exp2(fmaf(Sa[nb][3], k1, b4[3]));
            rsa[0] += a0; rsa[1] += a1; rsa[2] += a2; rsa[3] += a3;
            uint2v pk; pk[0] = packbf2(a0, a1); pk[1] = packbf2(a2, a3);
            *(uint2v*)(wa + nb * 16 + g * 4) = pk;
            float e0 = fast_exp2(fmaf(Sb[nb][0], k1, b4[0]));
            float e1 = fast_exp2(fmaf(Sb[nb][1], k1, b4[1]));
            float e2 = fast_exp2(fmaf(Sb[nb][2], k1, b4[2]));
            float e3 = fast_exp2(fmaf(Sb[nb][3], k1, b4[3]));
            rsb[0] += e0; rsb[1] += e1; rsb[2] += e2; rsb[3] += e3;
            uint2v qk; qk[0] = packbf2(e0, e1); qk[1] = packbf2(e2, e3);
            *(uint2v*)(wb + nb * 16 + g * 4) = qk;
        }
        bp += 64;
    }

    {
        short8 vf[2][2];
#pragma unroll
        for (int kb = 0; kb < 2; ++kb)
#pragma unroll
            for (int db = 0; db < 2; ++db)
                vf[kb][db] = *(const short8*)(vp + (size_t)db * 16 * L_ + kb * 32);
#pragma unroll
        for (int kb = 0; kb < 2; ++kb) {
            short8 af = *(const short8*)(pa1 + kb * 32 + g * 8);
            Oa[0] = __builtin_amdgcn_mfma_f32_16x16x32_bf16(af, vf[kb][0], Oa[0], 0, 0, 0);
            Oa[1] = __builtin_amdgcn_mfma_f32_16x16x32_bf16(af, vf[kb][1], Oa[1], 0, 0, 0);
        }
#pragma unroll
        for (int kb = 0; kb < 2; ++kb) {
            short8 bf = *(const short8*)(pb1 + kb * 32 + g * 8);
            Ob[0] = __builtin_amdgcn_mfma_f32_16x16x32_bf16(bf, vf[kb][0], Ob[0], 0, 0, 0);
            Ob[1] = __builtin_amdgcn_mfma_f32_16x16x32_bf16(bf, vf[kb][1], Ob[1], 0, 0, 0);
        }
    }

    float ra = (rsa[0] + rsa[1]) + (rsa[2] + rsa[3]);
    float rb = (rsb[0] + rsb[1]) + (rsb[2] + rsb[3]);
    ra += __shfl_xor(ra, 16, 64); ra += __shfl_xor(ra, 32, 64);
    rb += __shfl_xor(rb, 16, 64); rb += __shfl_xor(rb, 32, 64);
#pragma unroll
    for (int r = 0; r < 4; ++r) {
        float inva = 1.f / __shfl(ra, g * 4 + r, 64);
        float invb = 1.f / __shfl(rb, g * 4 + r, 64);
        size_t rowa = (size_t)n * L_ + q0 + wave * 16 + g * 4 + r;
        size_t rowb = rowa + 64;
#pragma unroll
        for (int db = 0; db < 2; ++db) {
            x_ws[rowa * E_ + h * HD_ + db * 16 + m] = f2b(Oa[db][r] * inva);
            x_ws[rowb * E_ + h * HD_ + db * 16 + m] = f2b(Ob[db][r] * invb);
        }
    }
}

// ---------------------------------------------------------------------------
// Kernel 3: C = X(bf16) @ Wo^T(bf16, pre-converted by proj) + bo, fp32 out.
// 64x64 tile, BK=64, 1024 blocks, XCD-swizzled, register-prefetch pipeline.
// Pure short8 staging (no conversion VALU).
// ---------------------------------------------------------------------------
__global__ __launch_bounds__(256) void out_gemm_kernel(
    const ushort* __restrict__ X, const ushort* __restrict__ wo_bf,
    const float* __restrict__ bo, float* __restrict__ C)
{
    const int B = blockIdx.x;
    const int it = ((B >> 7) << 3) + (B & 7);   // 0..63
    const int jt = (B >> 3) & 15;               // 0..15
    const int i0 = it * 64, j0 = jt * 64;

    const int t = threadIdx.x, wave = t >> 6, lane = t & 63;
    const int m = lane & 15, g = lane >> 4;

    __shared__ ushort sA[64][72];
    __shared__ ushort sB[64][72];

    float4v acc[4];
#pragma unroll
    for (int nb = 0; nb < 4; ++nb) acc[nb] = float4v{0.f,0.f,0.f,0.f};

    const int r0 = t >> 2;          // 0..63
    const int c0 = (t & 3) * 16;    // 0..48

    const ushort* xp = X + (size_t)(i0 + r0) * E_ + c0;
    const ushort* wp = wo_bf + (size_t)(j0 + r0) * E_ + c0;

    short8 xr0 = *(const short8*)xp;
    short8 xr1 = *(const short8*)(xp + 8);
    short8 wr0 = *(const short8*)wp;
    short8 wr1 = *(const short8*)(wp + 8);

    for (int k0 = 0; k0 < E_; k0 += 64) {
        __syncthreads();
        *(short8*)&sA[r0][c0]     = xr0;
        *(short8*)&sA[r0][c0 + 8] = xr1;
        *(short8*)&sB[r0][c0]     = wr0;
        *(short8*)&sB[r0][c0 + 8] = wr1;
        __syncthreads();
        if (k0 + 64 < E_) {   // uniform; prefetch next k-tile during compute
            xr0 = *(const short8*)(xp + k0 + 64);
            xr1 = *(const short8*)(xp + k0 + 72);
            wr0 = *(const short8*)(wp + k0 + 64);
            wr1 = *(const short8*)(wp + k0 + 72);
        }
#pragma unroll
        for (int kb = 0; kb < 2; ++kb) {
            short8 afr = *(const short8*)&sA[wave * 16 + m][kb * 32 + g * 8];
#pragma unroll
            for (int nb = 0; nb < 4; ++nb) {
                short8 bfr = *(const short8*)&sB[nb * 16 + m][kb * 32 + g * 8];
                acc[nb] = __builtin_amdgcn_mfma_f32_16x16x32_bf16(afr, bfr, acc[nb], 0, 0, 0);
            }
        }
    }

#pragma unroll
    for (int nb = 0; nb < 4; ++nb) {
        int col = j0 + nb * 16 + m;
        float bias = bo[col];
#pragma unroll
        for (int r = 0; r < 4; ++r) {
            int rowi = i0 + wave * 16 + g * 4 + r;
            C[(size_t)rowi * E_ + col] = acc[nb][r] + bias;
        }
    }
}

// ---------------------------------------------------------------------------
extern "C" void kernel_launch(void* const* d_in, const int* in_sizes, int n_in,
                              void* d_out, int out_size, void* d_ws, size_t ws_size,
                              hipStream_t stream) {
    const float* values = (const float*)d_in[0];
    const float* keys   = (const float*)d_in[1];
    const float* query  = (const float*)d_in[2];
    const int*   mask   = (const int*)d_in[3];
    const float* Wv     = (const float*)d_in[4];
    const float* Wk     = (const float*)d_in[5];
    const float* Wq     = (const float*)d_in[6];
    const float* Wo     = (const float*)d_in[7];
    const float* bo     = (const float*)d_in[8];
    float* out = (float*)d_out;

    const size_t M4 = (size_t)N_ * H_ * L_ * HD_;   // 4 Mi elements
    ushort* q_ws   = (ushort*)d_ws;
    ushort* k_ws   = q_ws + M4;
    ushort* vt_ws  = k_ws + M4;
    ushort* x_ws   = vt_ws + M4;
    ushort* wo_bf  = x_ws + M4;                     // 1 Mi ushort
    float*  bias_f = (float*)(wo_bf + (size_t)E_ * E_);  // 4096 floats

    proj_kernel<<<dim3(L_ / 64, H_, N_), 256, 0, stream>>>(
        values, keys, query, Wv, Wk, Wq, Wo, mask,
        vt_ws, k_ws, q_ws, wo_bf, bias_f);

    attn_kernel<<<dim3(1024), 256, 0, stream>>>(
        q_ws, k_ws, vt_ws, bias_f, x_ws);

    out_gemm_kernel<<<dim3(1024), 256, 0, stream>>>(
        x_ws, wo_bf, bo, out);
}